// Round 14
// baseline (78.057 us; speedup 1.0000x reference)
//
#include <hip/hip_runtime.h>
#include <math.h>

#define HX 48
#define WX 48
#define OMC 216
#define HY 96
#define WY 96

typedef __attribute__((ext_vector_type(8))) short bf16x8;
typedef __attribute__((ext_vector_type(4))) float f32x4;

__device__ inline unsigned short f2bf(float f) {
  unsigned u = __float_as_uint(f);
  return (unsigned short)((u + 0x7fffu + ((u >> 16) & 1u)) >> 16);  // RNE
}
__device__ inline unsigned pk2(float a, float b) {
  return (unsigned)f2bf(a) | ((unsigned)f2bf(b) << 16);
}

// ws layout (floats):
//  om  @ 0          : 1,990,656
//  ap2 @ 1,990,656  :    73,728   (147,456 bf16)
//  ap1 @ 2,064,384  :    18,432   ( 36,864 bf16)
//  yt  @ 2,082,816  : 2,359,296

// ---------- fused: prep (blocks 0..719) + ytr (blocks 720..1295) ----------
__global__ __launch_bounds__(256) void prep_ytr_kernel(
    const float* __restrict__ w_om, const float* __restrict__ w_dc,
    const float* __restrict__ y,
    unsigned short* __restrict__ ap2, unsigned short* __restrict__ ap1,
    float* __restrict__ yt) {
  __shared__ float tile[64][65];
  int bid = blockIdx.x;
  int t = threadIdx.x;
  if (bid < 720) {
    int idx = bid * 256 + t;                  // 0..184319
    if (idx < 147456) {
      int j = idx & 7;
      int tmp = idx >> 3;
      int l = tmp & 63; tmp >>= 6;
      int m = tmp & 15; tmp >>= 4;            // 0..17
      int s = tmp % 6, p = tmp / 6;
      int oc = m * 16 + (l & 15);
      int kk = s * 32 + (l >> 4) * 8 + j;     // 0..191
      int tap = kk >> 6, c = kk & 63;
      int k = p * 3 + tap;
      ap2[idx] = (oc < OMC) ? f2bf(w_om[oc * 576 + c * 9 + k]) : (unsigned short)0;
    } else {
      int i2 = idx - 147456;                  // < 36864
      int j = i2 & 7;
      int tmp = i2 >> 3;
      int l = tmp & 63; tmp >>= 6;
      int w = tmp & 3; tmp >>= 2;             // 0..17
      int s = tmp % 6, p = tmp / 6;
      int oc = w * 16 + (l & 15);
      int kk = s * 32 + (l >> 4) * 8 + j;
      int tap = kk >> 6, c = kk & 63;
      ap1[i2] = f2bf(w_dc[oc * 576 + c * 9 + p * 3 + tap]);
    }
  } else {
    int blk = bid - 720;                      // 576 = 4b * 144
    int b = blk / 144;
    int p0 = (blk % 144) * 64;
    int pl = t & 63;
    int cb = t >> 6;
#pragma unroll
    for (int i = 0; i < 16; ++i) {
      int c = cb * 16 + i;
      tile[c][pl] = y[((size_t)(b * 64 + c)) * 9216 + p0 + pl];
    }
    __syncthreads();
    int cw = t & 63;
    int pb = t >> 6;
#pragma unroll
    for (int i = 0; i < 16; ++i) {
      int p = pb * 16 + i;
      yt[((size_t)(b * 9216 + p0 + p)) * 64 + cw] = tile[cw][p];
    }
  }
}

// ---------- conv (9 taps) via MFMA, oc-split: 128oc x 16px per block ----------
__global__ __launch_bounds__(256) void conv_mfma_kernel(
    const float* __restrict__ x, const unsigned short* __restrict__ ap2,
    const float* __restrict__ bom, float* __restrict__ om) {
  __shared__ unsigned short sB[9][16][72];    // 20736 B, [tap][px][c]
  int t = threadIdx.x;
  int bid = blockIdx.x;                       // 1152
  int logical = (bid & 7) * 144 + (bid >> 3); // bijective XCD swizzle
  int och = logical / 576;                    // oc half
  int rem = logical % 576;
  int b = rem / 144;
  int tl = rem % 144;
  int h0 = (tl / 12) * 4;
  int w0 = (tl % 12) * 4;
  int s_ic = t >> 2;
  int s_row = t & 3;
  const float* xp = x + (size_t)b * 64 * 2304 + (size_t)s_ic * 2304;

#pragma unroll
  for (int k = 0; k < 9; ++k) {
    int dy = k / 3 - 1, dx = k % 3 - 1;
    int hh = h0 + s_row + dy;
    int ww = w0 + dx;
    bool hv = (unsigned)hh < (unsigned)HX;
    int hc = min(max(hh, 0), HX - 1);
    const float* xr = xp + hc * WX;
#pragma unroll
    for (int j = 0; j < 4; ++j) {
      int wcj = min(max(ww + j, 0), WX - 1);
      float v = xr[wcj] * ((hv && (unsigned)(ww + j) < (unsigned)WX) ? 1.f : 0.f);
      sB[k][s_row * 4 + j][s_ic] = f2bf(v);
    }
  }
  __syncthreads();

  int w = t >> 6;
  int l = t & 63;
  int lr = l & 15;
  int lg = l >> 4;
  f32x4 acc[2] = {};
#pragma unroll
  for (int p = 0; p < 3; ++p) {
#pragma unroll
    for (int s = 0; s < 6; ++s) {
      int tapidx = p * 3 + (s >> 1);
      int c0 = (s & 1) * 32;
      bf16x8 bv = *(const bf16x8*)&sB[tapidx][lr][c0 + lg * 8];
#pragma unroll
      for (int m = 0; m < 2; ++m) {
        int mq = och * 8 + w * 2 + m;         // 0..15
        bf16x8 av = *(const bf16x8*)(ap2 +
            (size_t)((((p * 6 + s) * 16) + mq) * 64 + l) * 8);
        acc[m] = __builtin_amdgcn_mfma_f32_16x16x32_bf16(av, bv, acc[m], 0, 0, 0);
      }
    }
  }
  int prow = lr >> 2, pcol = lr & 3;
#pragma unroll
  for (int m = 0; m < 2; ++m) {
    int ocb = (och * 8 + w * 2 + m) * 16 + lg * 4;
    if (ocb < OMC) {
      float4 bb = *(const float4*)&bom[ocb];
      float bvv[4] = {bb.x, bb.y, bb.z, bb.w};
#pragma unroll
      for (int i = 0; i < 4; ++i) {
        om[((size_t)(b * OMC + ocb + i)) * 2304 + (h0 + prow) * WX + w0 + pcol] =
            acc[m][i] + bvv[i];
      }
    }
  }
}

// ---------- deform: triples precomputed to LDS, pipelined gather + MFMA ----------
// NOTE: 3rd macro param must NOT be named w/x/y/z/s/d — member-access capture!
#define MAD4(d, s, mw)                                                  \
  d.x += (mw) * s.x; d.y += (mw) * s.y; d.z += (mw) * s.z; d.w += (mw) * s.w;

__global__ __launch_bounds__(256) void deform_mfma_kernel(
    const float* __restrict__ yt, const float* __restrict__ om,
    const unsigned short* __restrict__ ap1, const float* __restrict__ bdc,
    float* __restrict__ out) {
  __shared__ float sTy[72][16];                 // 4608 B  [k*8+g][px]
  __shared__ float sTx[72][16];                 // 4608 B
  __shared__ float sTm[72][16];                 // 4608 B
  __shared__ unsigned short sval[2][16][72];    // 4608 B   (total 18432 B)
  int t = threadIdx.x;
  int bid = blockIdx.x;                         // 2304
  int logical = (bid & 7) * 288 + (bid >> 3);   // bijective XCD swizzle
  int b = logical / 576;
  int tl = logical % 576;
  int h0 = (tl / 24) * 4;                       // 24 h-tiles of 4
  int w0 = (tl % 24) * 4;                       // 24 w-tiles of 4
  const float* omb = om + (size_t)b * OMC * 2304;
  const float* ytb = yt + (size_t)b * 9216 * 64;

  // ---- Phase A: compute all 1152 resize triples once (no cp duplication) ----
#pragma unroll
  for (int r = 0; r < 5; ++r) {
    int j = t + r * 256;
    if (j < 1152) {
      int k = j >> 7;                           // 0..8
      int g = (j >> 4) & 7;
      int px = j & 15;
      int gh = h0 + (px >> 2);
      int gw = w0 + (px & 3);
      float sh = fmaxf(gh * 0.5f - 0.25f, 0.f);
      float sw = fmaxf(gw * 0.5f - 0.25f, 0.f);
      int i0h = (int)sh; float th = sh - (float)i0h;
      int i0w = (int)sw; float tw = sw - (float)i0w;
      int i1h = min(i0h + 1, HX - 1);
      int i1w = min(i0w + 1, WX - 1);
      float r00 = (1.f - th) * (1.f - tw), r01 = (1.f - th) * tw;
      float r10 = th * (1.f - tw),         r11 = th * tw;
      int a00 = i0h * WX + i0w, a01 = i0h * WX + i1w;
      int a10 = i1h * WX + i0w, a11 = i1h * WX + i1w;
      const float* cy = omb + (size_t)(g * 18 + k * 2) * 2304;
      const float* cx = cy + 2304;
      const float* cm = omb + (size_t)(144 + g * 9 + k) * 2304;
      float oy = r00 * cy[a00] + r01 * cy[a01] + r10 * cy[a10] + r11 * cy[a11];
      float ox = r00 * cx[a00] + r01 * cx[a01] + r10 * cx[a10] + r11 * cx[a11];
      float mv = r00 * cm[a00] + r01 * cm[a01] + r10 * cm[a10] + r11 * cm[a11];
      int row = k * 8 + g;
      sTy[row][px] = (float)(gh + k / 3 - 1) + oy;
      sTx[row][px] = (float)(gw + k % 3 - 1) + ox;
      sTm[row][px] = 1.f / (1.f + __expf(-mv));
    }
  }

  int item = t >> 1;                            // 0..127 = g*16 + px
  int g = item >> 4;
  int px = item & 15;
  int cp = t & 1;                               // channel half of the 8-ch group
  int chb = g * 8 + cp * 4;

  int w = t >> 6;
  int l = t & 63;
  int lr = l & 15;
  int lg = l >> 4;

  __syncthreads();                              // triples ready

  float4 C[2][4];     // corner loads, slot tap&1
  float W[2][4];      // corner weights, slot tap&1

  auto issueC = [&](int k, float4* Co, float* Wo) {
    int row = k * 8 + g;
    float py = sTy[row][px], pxf = sTx[row][px], m = sTm[row][px];
    float y0f = floorf(py), x0f = floorf(pxf);
    float ty = py - y0f, tx = pxf - x0f;
    int y0 = (int)y0f, x0 = (int)x0f;
    int y1 = y0 + 1, x1 = x0 + 1;
    float w00 = (1.f - ty) * (1.f - tx) * m, w01 = (1.f - ty) * tx * m;
    float w10 = ty * (1.f - tx) * m,         w11 = ty * tx * m;
    Wo[0] = ((unsigned)y0 < HY && (unsigned)x0 < WY) ? w00 : 0.f;
    Wo[1] = ((unsigned)y0 < HY && (unsigned)x1 < WY) ? w01 : 0.f;
    Wo[2] = ((unsigned)y1 < HY && (unsigned)x0 < WY) ? w10 : 0.f;
    Wo[3] = ((unsigned)y1 < HY && (unsigned)x1 < WY) ? w11 : 0.f;
    int y0c = min(max(y0, 0), HY - 1), y1c = min(max(y1, 0), HY - 1);
    int x0c = min(max(x0, 0), WY - 1), x1c = min(max(x1, 0), WY - 1);
    Co[0] = *(const float4*)(ytb + (size_t)(y0c * WY + x0c) * 64 + chb);
    Co[1] = *(const float4*)(ytb + (size_t)(y0c * WY + x1c) * 64 + chb);
    Co[2] = *(const float4*)(ytb + (size_t)(y1c * WY + x0c) * 64 + chb);
    Co[3] = *(const float4*)(ytb + (size_t)(y1c * WY + x1c) * 64 + chb);
  };
  auto finishC = [&](const float4* Ci, const float* Wi, int buf) {
    float4 s0 = {0, 0, 0, 0};
    MAD4(s0, Ci[0], Wi[0]) MAD4(s0, Ci[1], Wi[1])
    MAD4(s0, Ci[2], Wi[2]) MAD4(s0, Ci[3], Wi[3])
    *(uint2*)&sval[buf][px][chb] = make_uint2(pk2(s0.x, s0.y), pk2(s0.z, s0.w));
  };

  // prologue: tap 0 corner loads in flight
  issueC(0, C[0], W[0]);

  f32x4 acc = {};
#pragma unroll
  for (int tp = 0; tp < 9; ++tp) {
    if (tp + 1 < 9)                              // next tap: 1-iter flight
      issueC(tp + 1, C[(tp + 1) & 1], W[(tp + 1) & 1]);
    finishC(C[tp & 1], W[tp & 1], tp & 1);       // issued last iter
    __syncthreads();
    int p = tp / 3;
    int sl = (tp % 3) * 2;
#pragma unroll
    for (int half = 0; half < 2; ++half) {
      int s = sl + half;
      bf16x8 av = *(const bf16x8*)(ap1 +
          (size_t)(((p * 6 + s) * 4 + w) * 64 + l) * 8);
      bf16x8 bv = *(const bf16x8*)&sval[tp & 1][lr][half * 32 + lg * 8];
      acc = __builtin_amdgcn_mfma_f32_16x16x32_bf16(av, bv, acc, 0, 0, 0);
    }
    // finishC[tp+2] (same buf) is fenced by barrier[tp+1] which program-order
    // follows this MFMA's LDS reads on every wave.
  }

  // epilogue: bias + relu + store (oc = w*16+lg*4+i, px = lr in 4x4 tile)
  float4 bb = *(const float4*)&bdc[w * 16 + lg * 4];
  float bvv[4] = {bb.x, bb.y, bb.z, bb.w};
#pragma unroll
  for (int i = 0; i < 4; ++i) {
    int oc = w * 16 + lg * 4 + i;
    out[((size_t)(b * 64 + oc) * 96 + h0 + (lr >> 2)) * 96 + w0 + (lr & 3)] =
        fmaxf(acc[i] + bvv[i], 0.f);
  }
}

extern "C" void kernel_launch(void* const* d_in, const int* in_sizes, int n_in,
                              void* d_out, int out_size, void* d_ws, size_t ws_size,
                              hipStream_t stream) {
  const float* x = (const float*)d_in[0];
  const float* y = (const float*)d_in[1];
  const float* w_om = (const float*)d_in[2];
  const float* b_om = (const float*)d_in[3];
  const float* w_dc = (const float*)d_in[4];
  const float* b_dc = (const float*)d_in[5];
  float* out = (float*)d_out;

  float* om  = (float*)d_ws;                       // 1,990,656 f
  unsigned short* ap2 = (unsigned short*)(om + 1990656);   // 147,456 bf16
  unsigned short* ap1 = ap2 + 147456;              //  36,864 bf16
  float* yt  = (float*)(ap1 + 36864);              // 2,359,296 f

  prep_ytr_kernel<<<1296, 256, 0, stream>>>(w_om, w_dc, y, ap2, ap1, yt);
  conv_mfma_kernel<<<1152, 256, 0, stream>>>(x, ap2, b_om, om);
  deform_mfma_kernel<<<2304, 256, 0, stream>>>(yt, om, ap1, b_dc, out);
}

// Round 16
// 64.890 us; speedup vs baseline: 1.2029x; 1.2029x over previous
//
#include <hip/hip_runtime.h>
#include <math.h>

#define HX 48
#define WX 48
#define OMC 216
#define HY 96
#define WY 96

typedef __attribute__((ext_vector_type(8))) short bf16x8;
typedef __attribute__((ext_vector_type(4))) float f32x4;

__device__ inline unsigned short f2bf(float f) {
  unsigned u = __float_as_uint(f);
  return (unsigned short)((u + 0x7fffu + ((u >> 16) & 1u)) >> 16);  // RNE
}
__device__ inline unsigned pk2(float a, float b) {
  return (unsigned)f2bf(a) | ((unsigned)f2bf(b) << 16);
}

// ws layout (floats):
//  om  @ 0          : 1,990,656
//  ap2 @ 1,990,656  :    73,728   (147,456 bf16)
//  ap1 @ 2,064,384  :    18,432   ( 36,864 bf16)
//  yt  @ 2,082,816  : 2,359,296

// ---------- fused: prep (blocks 0..719) + ytr (blocks 720..1295) ----------
__global__ __launch_bounds__(256) void prep_ytr_kernel(
    const float* __restrict__ w_om, const float* __restrict__ w_dc,
    const float* __restrict__ y,
    unsigned short* __restrict__ ap2, unsigned short* __restrict__ ap1,
    float* __restrict__ yt) {
  __shared__ float tile[64][65];
  int bid = blockIdx.x;
  int t = threadIdx.x;
  if (bid < 720) {
    int idx = bid * 256 + t;                  // 0..184319
    if (idx < 147456) {
      int j = idx & 7;
      int tmp = idx >> 3;
      int l = tmp & 63; tmp >>= 6;
      int m = tmp & 15; tmp >>= 4;            // 0..17
      int s = tmp % 6, p = tmp / 6;
      int oc = m * 16 + (l & 15);
      int kk = s * 32 + (l >> 4) * 8 + j;     // 0..191
      int tap = kk >> 6, c = kk & 63;
      int k = p * 3 + tap;
      ap2[idx] = (oc < OMC) ? f2bf(w_om[oc * 576 + c * 9 + k]) : (unsigned short)0;
    } else {
      int i2 = idx - 147456;                  // < 36864
      int j = i2 & 7;
      int tmp = i2 >> 3;
      int l = tmp & 63; tmp >>= 6;
      int w = tmp & 3; tmp >>= 2;             // 0..17
      int s = tmp % 6, p = tmp / 6;
      int oc = w * 16 + (l & 15);
      int kk = s * 32 + (l >> 4) * 8 + j;
      int tap = kk >> 6, c = kk & 63;
      ap1[i2] = f2bf(w_dc[oc * 576 + c * 9 + p * 3 + tap]);
    }
  } else {
    int blk = bid - 720;                      // 576 = 4b * 144
    int b = blk / 144;
    int p0 = (blk % 144) * 64;
    int pl = t & 63;
    int cb = t >> 6;
#pragma unroll
    for (int i = 0; i < 16; ++i) {
      int c = cb * 16 + i;
      tile[c][pl] = y[((size_t)(b * 64 + c)) * 9216 + p0 + pl];
    }
    __syncthreads();
    int cw = t & 63;
    int pb = t >> 6;
#pragma unroll
    for (int i = 0; i < 16; ++i) {
      int p = pb * 16 + i;
      yt[((size_t)(b * 9216 + p0 + p)) * 64 + cw] = tile[cw][p];
    }
  }
}

// ---------- conv (9 taps) via MFMA, oc-split; float4 register staging ----------
__global__ __launch_bounds__(256) void conv_mfma_kernel(
    const float* __restrict__ x, const unsigned short* __restrict__ ap2,
    const float* __restrict__ bom, float* __restrict__ om) {
  __shared__ unsigned short sB[9][16][72];    // 20736 B, [tap][px][c]
  int t = threadIdx.x;
  int bid = blockIdx.x;                       // 1152
  int logical = (bid & 7) * 144 + (bid >> 3); // bijective XCD swizzle
  int och = logical / 576;                    // oc half
  int rem = logical % 576;
  int b = rem / 144;
  int tl = rem % 144;
  int h0 = (tl / 12) * 4;
  int w0 = (tl % 12) * 4;
  int s_ic = t >> 2;
  int s_row = t & 3;
  const float* xp = x + (size_t)b * 64 * 2304 + (size_t)s_ic * 2304;

  // coalesced staging: 3 rows (dy=-1,0,1) x 3 aligned float4 (cols w0-4..w0+7)
  // window index i (0..11) = column (w0-4+i); clamped bases only supply
  // values for columns the validity mask zeroes.
  float4 X[3][3];
  bool hvr[3];
#pragma unroll
  for (int r = 0; r < 3; ++r) {
    int hh = h0 + s_row + r - 1;
    hvr[r] = (unsigned)hh < (unsigned)HX;
    int hc = min(max(hh, 0), HX - 1);
    const float* xr = xp + hc * WX;
#pragma unroll
    for (int q = 0; q < 3; ++q) {
      int cb = min(max(w0 - 4 + 4 * q, 0), WX - 4);   // clamped aligned base
      X[r][q] = *(const float4*)&xr[cb];
    }
  }
#pragma unroll
  for (int k = 0; k < 9; ++k) {
    int dy = k / 3 - 1, dx = k % 3 - 1;
    int r = dy + 1;
#pragma unroll
    for (int j = 0; j < 4; ++j) {
      int idx = j + dx + 4;                   // column (w0+j+dx) -> idx 3..8
      int q = idx >> 2, e = idx & 3;
      float val = (e == 0) ? X[r][q].x : (e == 1) ? X[r][q].y
                : (e == 2) ? X[r][q].z : X[r][q].w;
      bool cv = (unsigned)(w0 + j + dx) < (unsigned)WX;
      float v = (hvr[r] && cv) ? val : 0.f;
      sB[k][s_row * 4 + j][s_ic] = f2bf(v);
    }
  }
  __syncthreads();

  int w = t >> 6;
  int l = t & 63;
  int lr = l & 15;
  int lg = l >> 4;
  f32x4 acc[2] = {};
#pragma unroll
  for (int p = 0; p < 3; ++p) {
#pragma unroll
    for (int s = 0; s < 6; ++s) {
      int tapidx = p * 3 + (s >> 1);
      int c0 = (s & 1) * 32;
      bf16x8 bv = *(const bf16x8*)&sB[tapidx][lr][c0 + lg * 8];
#pragma unroll
      for (int m = 0; m < 2; ++m) {
        int mq = och * 8 + w * 2 + m;         // 0..15
        bf16x8 av = *(const bf16x8*)(ap2 +
            (size_t)((((p * 6 + s) * 16) + mq) * 64 + l) * 8);
        acc[m] = __builtin_amdgcn_mfma_f32_16x16x32_bf16(av, bv, acc[m], 0, 0, 0);
      }
    }
  }
  int prow = lr >> 2, pcol = lr & 3;
#pragma unroll
  for (int m = 0; m < 2; ++m) {
    int ocb = (och * 8 + w * 2 + m) * 16 + lg * 4;
    if (ocb < OMC) {
      float4 bb = *(const float4*)&bom[ocb];
      float bvv[4] = {bb.x, bb.y, bb.z, bb.w};
#pragma unroll
      for (int i = 0; i < 4; ++i) {
        om[((size_t)(b * OMC + ocb + i)) * 2304 + (h0 + prow) * WX + w0 + pcol] =
            acc[m][i] + bvv[i];
      }
    }
  }
}

// ---------- deform: triples in LDS, pinned pipelined gather + MFMA ----------
// NOTE: 3rd macro param must NOT be named w/x/y/z/s/d — member-access capture!
#define MAD4(d, s, mw)                                                  \
  d.x += (mw) * s.x; d.y += (mw) * s.y; d.z += (mw) * s.z; d.w += (mw) * s.w;

__global__ __launch_bounds__(256) void deform_mfma_kernel(
    const float* __restrict__ yt, const float* __restrict__ om,
    const unsigned short* __restrict__ ap1, const float* __restrict__ bdc,
    float* __restrict__ out) {
  __shared__ float sTy[72][16];                 // 4608 B  [k*8+g][px]
  __shared__ float sTx[72][16];                 // 4608 B
  __shared__ float sTm[72][16];                 // 4608 B
  __shared__ unsigned short sval[2][16][72];    // 4608 B   (total 18432 B)
  int t = threadIdx.x;
  int bid = blockIdx.x;                         // 2304
  int logical = (bid & 7) * 288 + (bid >> 3);   // bijective XCD swizzle
  int b = logical / 576;
  int tl = logical % 576;
  int h0 = (tl / 24) * 4;                       // 24 h-tiles of 4
  int w0 = (tl % 24) * 4;                       // 24 w-tiles of 4
  const float* omb = om + (size_t)b * OMC * 2304;
  const float* ytb = yt + (size_t)b * 9216 * 64;

  // ---- Phase A: compute all 1152 resize triples once (no cp duplication) ----
#pragma unroll
  for (int r = 0; r < 5; ++r) {
    int j = t + r * 256;
    if (j < 1152) {
      int k = j >> 7;                           // 0..8
      int g = (j >> 4) & 7;
      int px = j & 15;
      int gh = h0 + (px >> 2);
      int gw = w0 + (px & 3);
      float sh = fmaxf(gh * 0.5f - 0.25f, 0.f);
      float sw = fmaxf(gw * 0.5f - 0.25f, 0.f);
      int i0h = (int)sh; float th = sh - (float)i0h;
      int i0w = (int)sw; float tw = sw - (float)i0w;
      int i1h = min(i0h + 1, HX - 1);
      int i1w = min(i0w + 1, WX - 1);
      float r00 = (1.f - th) * (1.f - tw), r01 = (1.f - th) * tw;
      float r10 = th * (1.f - tw),         r11 = th * tw;
      int a00 = i0h * WX + i0w, a01 = i0h * WX + i1w;
      int a10 = i1h * WX + i0w, a11 = i1h * WX + i1w;
      const float* cy = omb + (size_t)(g * 18 + k * 2) * 2304;
      const float* cx = cy + 2304;
      const float* cm = omb + (size_t)(144 + g * 9 + k) * 2304;
      float oy = r00 * cy[a00] + r01 * cy[a01] + r10 * cy[a10] + r11 * cy[a11];
      float ox = r00 * cx[a00] + r01 * cx[a01] + r10 * cx[a10] + r11 * cx[a11];
      float mv = r00 * cm[a00] + r01 * cm[a01] + r10 * cm[a10] + r11 * cm[a11];
      int row = k * 8 + g;
      sTy[row][px] = (float)(gh + k / 3 - 1) + oy;
      sTx[row][px] = (float)(gw + k % 3 - 1) + ox;
      sTm[row][px] = 1.f / (1.f + __expf(-mv));
    }
  }

  int item = t >> 1;                            // 0..127 = g*16 + px
  int g = item >> 4;
  int px = item & 15;
  int cp = t & 1;                               // channel half of the 8-ch group
  int chb = g * 8 + cp * 4;

  int w = t >> 6;
  int l = t & 63;
  int lr = l & 15;
  int lg = l >> 4;

  __syncthreads();                              // triples ready

  float4 C[2][4];     // corner loads, slot tap&1
  float W[2][4];      // corner weights, slot tap&1

  auto issueC = [&](int k, float4* Co, float* Wo) {
    int row = k * 8 + g;
    float py = sTy[row][px], pxf = sTx[row][px], m = sTm[row][px];
    float y0f = floorf(py), x0f = floorf(pxf);
    float ty = py - y0f, tx = pxf - x0f;
    int y0 = (int)y0f, x0 = (int)x0f;
    int y1 = y0 + 1, x1 = x0 + 1;
    float w00 = (1.f - ty) * (1.f - tx) * m, w01 = (1.f - ty) * tx * m;
    float w10 = ty * (1.f - tx) * m,         w11 = ty * tx * m;
    Wo[0] = ((unsigned)y0 < HY && (unsigned)x0 < WY) ? w00 : 0.f;
    Wo[1] = ((unsigned)y0 < HY && (unsigned)x1 < WY) ? w01 : 0.f;
    Wo[2] = ((unsigned)y1 < HY && (unsigned)x0 < WY) ? w10 : 0.f;
    Wo[3] = ((unsigned)y1 < HY && (unsigned)x1 < WY) ? w11 : 0.f;
    int y0c = min(max(y0, 0), HY - 1), y1c = min(max(y1, 0), HY - 1);
    int x0c = min(max(x0, 0), WY - 1), x1c = min(max(x1, 0), WY - 1);
    Co[0] = *(const float4*)(ytb + (size_t)(y0c * WY + x0c) * 64 + chb);
    Co[1] = *(const float4*)(ytb + (size_t)(y0c * WY + x1c) * 64 + chb);
    Co[2] = *(const float4*)(ytb + (size_t)(y1c * WY + x0c) * 64 + chb);
    Co[3] = *(const float4*)(ytb + (size_t)(y1c * WY + x1c) * 64 + chb);
  };
  auto finishC = [&](const float4* Ci, const float* Wi, int buf) {
    float4 s0 = {0, 0, 0, 0};
    MAD4(s0, Ci[0], Wi[0]) MAD4(s0, Ci[1], Wi[1])
    MAD4(s0, Ci[2], Wi[2]) MAD4(s0, Ci[3], Wi[3])
    *(uint2*)&sval[buf][px][chb] = make_uint2(pk2(s0.x, s0.y), pk2(s0.z, s0.w));
  };

  // prologue: tap 0 corner loads in flight (pinned — may not sink)
  issueC(0, C[0], W[0]);
  __builtin_amdgcn_sched_barrier(0);

  f32x4 acc = {};
#pragma unroll
  for (int tp = 0; tp < 9; ++tp) {
    if (tp + 1 < 9) {                            // next tap: 1-iter flight
      issueC(tp + 1, C[(tp + 1) & 1], W[(tp + 1) & 1]);
      __builtin_amdgcn_sched_barrier(0);         // pin loads BEFORE finishC(tp)
    }
    finishC(C[tp & 1], W[tp & 1], tp & 1);       // waits only its own 4 loads
    __syncthreads();
    int p = tp / 3;
    int sl = (tp % 3) * 2;
#pragma unroll
    for (int half = 0; half < 2; ++half) {
      int s = sl + half;
      bf16x8 av = *(const bf16x8*)(ap1 +
          (size_t)(((p * 6 + s) * 4 + w) * 64 + l) * 8);
      bf16x8 bv = *(const bf16x8*)&sval[tp & 1][lr][half * 32 + lg * 8];
      acc = __builtin_amdgcn_mfma_f32_16x16x32_bf16(av, bv, acc, 0, 0, 0);
    }
    // finishC[tp+2] (same buf) is fenced by barrier[tp+1] which program-order
    // follows this MFMA's LDS reads on every wave.
  }

  // epilogue: bias + relu + store (oc = w*16+lg*4+i, px = lr in 4x4 tile)
  float4 bb = *(const float4*)&bdc[w * 16 + lg * 4];
  float bvv[4] = {bb.x, bb.y, bb.z, bb.w};
#pragma unroll
  for (int i = 0; i < 4; ++i) {
    int oc = w * 16 + lg * 4 + i;
    out[((size_t)(b * 64 + oc) * 96 + h0 + (lr >> 2)) * 96 + w0 + (lr & 3)] =
        fmaxf(acc[i] + bvv[i], 0.f);
  }
}

extern "C" void kernel_launch(void* const* d_in, const int* in_sizes, int n_in,
                              void* d_out, int out_size, void* d_ws, size_t ws_size,
                              hipStream_t stream) {
  const float* x = (const float*)d_in[0];
  const float* y = (const float*)d_in[1];
  const float* w_om = (const float*)d_in[2];
  const float* b_om = (const float*)d_in[3];
  const float* w_dc = (const float*)d_in[4];
  const float* b_dc = (const float*)d_in[5];
  float* out = (float*)d_out;

  float* om  = (float*)d_ws;                       // 1,990,656 f
  unsigned short* ap2 = (unsigned short*)(om + 1990656);   // 147,456 bf16
  unsigned short* ap1 = ap2 + 147456;              //  36,864 bf16
  float* yt  = (float*)(ap1 + 36864);              // 2,359,296 f

  prep_ytr_kernel<<<1296, 256, 0, stream>>>(w_om, w_dc, y, ap2, ap1, yt);
  conv_mfma_kernel<<<1152, 256, 0, stream>>>(x, ap2, b_om, om);
  deform_mfma_kernel<<<2304, 256, 0, stream>>>(yt, om, ap1, b_dc, out);
}

// Round 17
// 63.120 us; speedup vs baseline: 1.2366x; 1.0280x over previous
//
#include <hip/hip_runtime.h>
#include <math.h>

#define HX 48
#define WX 48
#define OMC 216
#define HY 96
#define WY 96

typedef __attribute__((ext_vector_type(8))) short bf16x8;
typedef __attribute__((ext_vector_type(4))) float f32x4;

__device__ inline unsigned short f2bf(float f) {
  unsigned u = __float_as_uint(f);
  return (unsigned short)((u + 0x7fffu + ((u >> 16) & 1u)) >> 16);  // RNE
}
__device__ inline unsigned pk2(float a, float b) {
  return (unsigned)f2bf(a) | ((unsigned)f2bf(b) << 16);
}

// ws layout (floats):
//  om   @ 0          : 1,990,656
//  ap2  @ 1,990,656  :    73,728  (147,456 bf16)
//  ap1  @ 2,064,384  :    18,432  ( 36,864 bf16)
//  ytbf @ 2,082,816  : 1,179,648  (2,359,296 bf16: [b][px9216][ch64])

// ---------- fused: prep (blocks 0..719) + ytr->bf16 (blocks 720..1295) ----------
__global__ __launch_bounds__(256) void prep_ytr_kernel(
    const float* __restrict__ w_om, const float* __restrict__ w_dc,
    const float* __restrict__ y,
    unsigned short* __restrict__ ap2, unsigned short* __restrict__ ap1,
    unsigned short* __restrict__ ytbf) {
  __shared__ float tile[64][65];
  int bid = blockIdx.x;
  int t = threadIdx.x;
  if (bid < 720) {
    int idx = bid * 256 + t;                  // 0..184319
    if (idx < 147456) {
      int j = idx & 7;
      int tmp = idx >> 3;
      int l = tmp & 63; tmp >>= 6;
      int m = tmp & 15; tmp >>= 4;            // 0..17
      int s = tmp % 6, p = tmp / 6;
      int oc = m * 16 + (l & 15);
      int kk = s * 32 + (l >> 4) * 8 + j;     // 0..191
      int tap = kk >> 6, c = kk & 63;
      int k = p * 3 + tap;
      ap2[idx] = (oc < OMC) ? f2bf(w_om[oc * 576 + c * 9 + k]) : (unsigned short)0;
    } else {
      int i2 = idx - 147456;                  // < 36864
      int j = i2 & 7;
      int tmp = i2 >> 3;
      int l = tmp & 63; tmp >>= 6;
      int w = tmp & 3; tmp >>= 2;             // 0..17
      int s = tmp % 6, p = tmp / 6;
      int oc = w * 16 + (l & 15);
      int kk = s * 32 + (l >> 4) * 8 + j;
      int tap = kk >> 6, c = kk & 63;
      ap1[i2] = f2bf(w_dc[oc * 576 + c * 9 + p * 3 + tap]);
    }
  } else {
    int blk = bid - 720;                      // 576 = 4b * 144
    int b = blk / 144;
    int p0 = (blk % 144) * 64;
    int pl = t & 63;
    int cb = t >> 6;
#pragma unroll
    for (int i = 0; i < 16; ++i) {
      int c = cb * 16 + i;
      tile[c][pl] = y[((size_t)(b * 64 + c)) * 9216 + p0 + pl];
    }
    __syncthreads();
    int cw = t & 63;
    int pb = t >> 6;
#pragma unroll
    for (int i = 0; i < 16; ++i) {
      int p = pb * 16 + i;
      ytbf[((size_t)(b * 9216 + p0 + p)) * 64 + cw] = f2bf(tile[cw][p]);
    }
  }
}

// ---------- conv (9 taps) via MFMA, oc-split; float4 register staging ----------
__global__ __launch_bounds__(256) void conv_mfma_kernel(
    const float* __restrict__ x, const unsigned short* __restrict__ ap2,
    const float* __restrict__ bom, float* __restrict__ om) {
  __shared__ unsigned short sB[9][16][72];    // 20736 B, [tap][px][c]
  int t = threadIdx.x;
  int bid = blockIdx.x;                       // 1152
  int logical = (bid & 7) * 144 + (bid >> 3); // bijective XCD swizzle
  int och = logical / 576;                    // oc half
  int rem = logical % 576;
  int b = rem / 144;
  int tl = rem % 144;
  int h0 = (tl / 12) * 4;
  int w0 = (tl % 12) * 4;
  int s_ic = t >> 2;
  int s_row = t & 3;
  const float* xp = x + (size_t)b * 64 * 2304 + (size_t)s_ic * 2304;

  float4 X[3][3];
  bool hvr[3];
#pragma unroll
  for (int r = 0; r < 3; ++r) {
    int hh = h0 + s_row + r - 1;
    hvr[r] = (unsigned)hh < (unsigned)HX;
    int hc = min(max(hh, 0), HX - 1);
    const float* xr = xp + hc * WX;
#pragma unroll
    for (int q = 0; q < 3; ++q) {
      int cb = min(max(w0 - 4 + 4 * q, 0), WX - 4);   // clamped aligned base
      X[r][q] = *(const float4*)&xr[cb];
    }
  }
#pragma unroll
  for (int k = 0; k < 9; ++k) {
    int dy = k / 3 - 1, dx = k % 3 - 1;
    int r = dy + 1;
#pragma unroll
    for (int j = 0; j < 4; ++j) {
      int idx = j + dx + 4;                   // column (w0+j+dx) -> idx 3..8
      int q = idx >> 2, e = idx & 3;
      float val = (e == 0) ? X[r][q].x : (e == 1) ? X[r][q].y
                : (e == 2) ? X[r][q].z : X[r][q].w;
      bool cv = (unsigned)(w0 + j + dx) < (unsigned)WX;
      float v = (hvr[r] && cv) ? val : 0.f;
      sB[k][s_row * 4 + j][s_ic] = f2bf(v);
    }
  }
  __syncthreads();

  int w = t >> 6;
  int l = t & 63;
  int lr = l & 15;
  int lg = l >> 4;
  f32x4 acc[2] = {};
#pragma unroll
  for (int p = 0; p < 3; ++p) {
#pragma unroll
    for (int s = 0; s < 6; ++s) {
      int tapidx = p * 3 + (s >> 1);
      int c0 = (s & 1) * 32;
      bf16x8 bv = *(const bf16x8*)&sB[tapidx][lr][c0 + lg * 8];
#pragma unroll
      for (int m = 0; m < 2; ++m) {
        int mq = och * 8 + w * 2 + m;         // 0..15
        bf16x8 av = *(const bf16x8*)(ap2 +
            (size_t)((((p * 6 + s) * 16) + mq) * 64 + l) * 8);
        acc[m] = __builtin_amdgcn_mfma_f32_16x16x32_bf16(av, bv, acc[m], 0, 0, 0);
      }
    }
  }
  int prow = lr >> 2, pcol = lr & 3;
#pragma unroll
  for (int m = 0; m < 2; ++m) {
    int ocb = (och * 8 + w * 2 + m) * 16 + lg * 4;
    if (ocb < OMC) {
      float4 bb = *(const float4*)&bom[ocb];
      float bvv[4] = {bb.x, bb.y, bb.z, bb.w};
#pragma unroll
      for (int i = 0; i < 4; ++i) {
        om[((size_t)(b * OMC + ocb + i)) * 2304 + (h0 + prow) * WX + w0 + pcol] =
            acc[m][i] + bvv[i];
      }
    }
  }
}

// ---------- deform: LDS-staged window gather + MFMA ----------
__global__ __launch_bounds__(256) void deform_mfma_kernel(
    const unsigned short* __restrict__ ytbf, const float* __restrict__ om,
    const unsigned short* __restrict__ ap1, const float* __restrict__ bdc,
    float* __restrict__ out) {
  __shared__ unsigned short sYt[144 * 64];      // 18432 B: 12x12 px window, swizzled
  __shared__ float sTy[72][16];                 // 4608 B  [k*8+g][px]
  __shared__ float sTx[72][16];                 // 4608 B
  __shared__ float sTm[72][16];                 // 4608 B
  __shared__ unsigned short sval[2][16][72];    // 4608 B   (total 36864 B)
  int t = threadIdx.x;
  int bid = blockIdx.x;                         // 2304
  int logical = (bid & 7) * 288 + (bid >> 3);   // bijective XCD swizzle
  int b = logical / 576;
  int tl = logical % 576;
  int h0 = (tl / 24) * 4;                       // 24 h-tiles of 4
  int w0 = (tl % 24) * 4;                       // 24 w-tiles of 4
  int wy0 = min(max(h0 - 4, 0), HY - 12);
  int wx0 = min(max(w0 - 4, 0), WY - 12);
  const float* omb = om + (size_t)b * OMC * 2304;
  const unsigned short* ytb = ytbf + (size_t)b * 9216 * 64;

  // ---- Stage window: 144 px x 128B, XOR-swizzled 16B granules ----
  for (int i = t; i < 1152; i += 256) {
    int pxl = i >> 3, part = i & 7;
    int ry = pxl / 12, rx = pxl - ry * 12;
    const unsigned short* src =
        ytb + ((size_t)((wy0 + ry) * WY + wx0 + rx) << 6) + part * 8;
    int gr = part ^ (pxl & 7);
    *(uint4*)&sYt[pxl * 64 + gr * 8] = *(const uint4*)src;
  }

  // ---- Phase A: all 1152 resize triples once ----
#pragma unroll
  for (int r = 0; r < 5; ++r) {
    int j = t + r * 256;
    if (j < 1152) {
      int k = j >> 7;                           // 0..8
      int g = (j >> 4) & 7;
      int px = j & 15;
      int gh = h0 + (px >> 2);
      int gw = w0 + (px & 3);
      float sh = fmaxf(gh * 0.5f - 0.25f, 0.f);
      float sw = fmaxf(gw * 0.5f - 0.25f, 0.f);
      int i0h = (int)sh; float th = sh - (float)i0h;
      int i0w = (int)sw; float tw = sw - (float)i0w;
      int i1h = min(i0h + 1, HX - 1);
      int i1w = min(i0w + 1, WX - 1);
      float r00 = (1.f - th) * (1.f - tw), r01 = (1.f - th) * tw;
      float r10 = th * (1.f - tw),         r11 = th * tw;
      int a00 = i0h * WX + i0w, a01 = i0h * WX + i1w;
      int a10 = i1h * WX + i0w, a11 = i1h * WX + i1w;
      const float* cy = omb + (size_t)(g * 18 + k * 2) * 2304;
      const float* cx = cy + 2304;
      const float* cm = omb + (size_t)(144 + g * 9 + k) * 2304;
      float oy = r00 * cy[a00] + r01 * cy[a01] + r10 * cy[a10] + r11 * cy[a11];
      float ox = r00 * cx[a00] + r01 * cx[a01] + r10 * cx[a10] + r11 * cx[a11];
      float mv = r00 * cm[a00] + r01 * cm[a01] + r10 * cm[a10] + r11 * cm[a11];
      int row = k * 8 + g;
      sTy[row][px] = (float)(gh + k / 3 - 1) + oy;
      sTx[row][px] = (float)(gw + k % 3 - 1) + ox;
      sTm[row][px] = 1.f / (1.f + __expf(-mv));
    }
  }

  int item = t >> 1;                            // 0..127 = g*16 + px
  int g = item >> 4;
  int px = item & 15;
  int cp = t & 1;                               // channel half of the 8-ch group
  int chb = g * 8 + cp * 4;

  int w = t >> 6;
  int l = t & 63;
  int lr = l & 15;
  int lg = l >> 4;

  __syncthreads();                              // window + triples ready

  f32x4 acc = {};
#pragma unroll
  for (int tp = 0; tp < 9; ++tp) {
    int row = tp * 8 + g;
    float py = sTy[row][px], pxf = sTx[row][px], m = sTm[row][px];
    float y0f = floorf(py), x0f = floorf(pxf);
    float ty = py - y0f, tx = pxf - x0f;
    int y0 = (int)y0f, x0 = (int)x0f;
    int y1 = y0 + 1, x1 = x0 + 1;
    float w00 = (1.f - ty) * (1.f - tx) * m, w01 = (1.f - ty) * tx * m;
    float w10 = ty * (1.f - tx) * m,         w11 = ty * tx * m;
    float W0 = ((unsigned)y0 < HY && (unsigned)x0 < WY) ? w00 : 0.f;
    float W1 = ((unsigned)y0 < HY && (unsigned)x1 < WY) ? w01 : 0.f;
    float W2 = ((unsigned)y1 < HY && (unsigned)x0 < WY) ? w10 : 0.f;
    float W3 = ((unsigned)y1 < HY && (unsigned)x1 < WY) ? w11 : 0.f;
    float4 s0 = {0.f, 0.f, 0.f, 0.f};

    auto corner = [&](int yy, int xx, float wgt) {
      int ly = yy - wy0, lx = xx - wx0;
      ushort4 v;
      if ((unsigned)ly < 12u && (unsigned)lx < 12u) {
        int pxl = ly * 12 + lx;
        v = *(const ushort4*)&sYt[pxl * 64 + ((g ^ (pxl & 7)) << 3) + cp * 4];
      } else {
        int yc = min(max(yy, 0), HY - 1), xc = min(max(xx, 0), WY - 1);
        v = *(const ushort4*)&ytb[((size_t)(yc * WY + xc) << 6) + chb];
      }
      s0.x += wgt * __uint_as_float((unsigned)v.x << 16);
      s0.y += wgt * __uint_as_float((unsigned)v.y << 16);
      s0.z += wgt * __uint_as_float((unsigned)v.z << 16);
      s0.w += wgt * __uint_as_float((unsigned)v.w << 16);
    };
    corner(y0, x0, W0);
    corner(y0, x1, W1);
    corner(y1, x0, W2);
    corner(y1, x1, W3);

    *(uint2*)&sval[tp & 1][px][chb] = make_uint2(pk2(s0.x, s0.y), pk2(s0.z, s0.w));
    __syncthreads();
    int p = tp / 3;
    int sl = (tp % 3) * 2;
#pragma unroll
    for (int half = 0; half < 2; ++half) {
      int s = sl + half;
      bf16x8 av = *(const bf16x8*)(ap1 +
          (size_t)(((p * 6 + s) * 4 + w) * 64 + l) * 8);
      bf16x8 bv = *(const bf16x8*)&sval[tp & 1][lr][half * 32 + lg * 8];
      acc = __builtin_amdgcn_mfma_f32_16x16x32_bf16(av, bv, acc, 0, 0, 0);
    }
    // next tap writes the other sval buffer; fenced by this tap's barrier.
  }

  // epilogue: bias + relu + store (oc = w*16+lg*4+i, px = lr in 4x4 tile)
  float4 bb = *(const float4*)&bdc[w * 16 + lg * 4];
  float bvv[4] = {bb.x, bb.y, bb.z, bb.w};
#pragma unroll
  for (int i = 0; i < 4; ++i) {
    int oc = w * 16 + lg * 4 + i;
    out[((size_t)(b * 64 + oc) * 96 + h0 + (lr >> 2)) * 96 + w0 + (lr & 3)] =
        fmaxf(acc[i] + bvv[i], 0.f);
  }
}

extern "C" void kernel_launch(void* const* d_in, const int* in_sizes, int n_in,
                              void* d_out, int out_size, void* d_ws, size_t ws_size,
                              hipStream_t stream) {
  const float* x = (const float*)d_in[0];
  const float* y = (const float*)d_in[1];
  const float* w_om = (const float*)d_in[2];
  const float* b_om = (const float*)d_in[3];
  const float* w_dc = (const float*)d_in[4];
  const float* b_dc = (const float*)d_in[5];
  float* out = (float*)d_out;

  float* om  = (float*)d_ws;                       // 1,990,656 f
  unsigned short* ap2 = (unsigned short*)(om + 1990656);   // 147,456 bf16
  unsigned short* ap1 = ap2 + 147456;              //  36,864 bf16
  unsigned short* ytbf = ap1 + 36864;              // 2,359,296 bf16

  prep_ytr_kernel<<<1296, 256, 0, stream>>>(w_om, w_dc, y, ap2, ap1, ytbf);
  conv_mfma_kernel<<<1152, 256, 0, stream>>>(x, ap2, b_om, om);
  deform_mfma_kernel<<<2304, 256, 0, stream>>>(ytbf, om, ap1, b_dc, out);
}

// Round 18
// 62.668 us; speedup vs baseline: 1.2456x; 1.0072x over previous
//
#include <hip/hip_runtime.h>
#include <math.h>

#define HX 48
#define WX 48
#define OMC 216
#define HY 96
#define WY 96

typedef __attribute__((ext_vector_type(8))) short bf16x8;
typedef __attribute__((ext_vector_type(4))) float f32x4;

__device__ inline unsigned short f2bf(float f) {
  unsigned u = __float_as_uint(f);
  return (unsigned short)((u + 0x7fffu + ((u >> 16) & 1u)) >> 16);  // RNE
}
__device__ inline unsigned pk2(float a, float b) {
  return (unsigned)f2bf(a) | ((unsigned)f2bf(b) << 16);
}
#define B2F(u) __uint_as_float((unsigned)(u) << 16)

// ws layout (floats):
//  om   @ 0          : 1,990,656
//  ap2  @ 1,990,656  :    73,728  (147,456 bf16)
//  ap1  @ 2,064,384  :    18,432  ( 36,864 bf16)
//  ytbf @ 2,082,816  : 1,179,648  (2,359,296 bf16: [b][px9216][ch64])

// ---------- fused: prep (blocks 0..719) + ytr->bf16 (blocks 720..1295) ----------
__global__ __launch_bounds__(256) void prep_ytr_kernel(
    const float* __restrict__ w_om, const float* __restrict__ w_dc,
    const float* __restrict__ y,
    unsigned short* __restrict__ ap2, unsigned short* __restrict__ ap1,
    unsigned short* __restrict__ ytbf) {
  __shared__ float tile[64][65];
  int bid = blockIdx.x;
  int t = threadIdx.x;
  if (bid < 720) {
    int idx = bid * 256 + t;                  // 0..184319
    if (idx < 147456) {
      int j = idx & 7;
      int tmp = idx >> 3;
      int l = tmp & 63; tmp >>= 6;
      int m = tmp & 15; tmp >>= 4;            // 0..17
      int s = tmp % 6, p = tmp / 6;
      int oc = m * 16 + (l & 15);
      int kk = s * 32 + (l >> 4) * 8 + j;     // 0..191
      int tap = kk >> 6, c = kk & 63;
      int k = p * 3 + tap;
      ap2[idx] = (oc < OMC) ? f2bf(w_om[oc * 576 + c * 9 + k]) : (unsigned short)0;
    } else {
      int i2 = idx - 147456;                  // < 36864
      int j = i2 & 7;
      int tmp = i2 >> 3;
      int l = tmp & 63; tmp >>= 6;
      int w = tmp & 3; tmp >>= 2;             // 0..17
      int s = tmp % 6, p = tmp / 6;
      int oc = w * 16 + (l & 15);
      int kk = s * 32 + (l >> 4) * 8 + j;
      int tap = kk >> 6, c = kk & 63;
      ap1[i2] = f2bf(w_dc[oc * 576 + c * 9 + p * 3 + tap]);
    }
  } else {
    int blk = bid - 720;                      // 576 = 4b * 144
    int b = blk / 144;
    int p0 = (blk % 144) * 64;
    int pl = t & 63;
    int cb = t >> 6;
#pragma unroll
    for (int i = 0; i < 16; ++i) {
      int c = cb * 16 + i;
      tile[c][pl] = y[((size_t)(b * 64 + c)) * 9216 + p0 + pl];
    }
    __syncthreads();
    int cw = t & 63;
    int pb = t >> 6;
#pragma unroll
    for (int i = 0; i < 16; ++i) {
      int p = pb * 16 + i;
      ytbf[((size_t)(b * 9216 + p0 + p)) * 64 + cw] = f2bf(tile[cw][p]);
    }
  }
}

// ---------- conv (9 taps) via MFMA, oc-split; float4 register staging ----------
__global__ __launch_bounds__(256) void conv_mfma_kernel(
    const float* __restrict__ x, const unsigned short* __restrict__ ap2,
    const float* __restrict__ bom, float* __restrict__ om) {
  __shared__ unsigned short sB[9][16][72];    // 20736 B, [tap][px][c]
  int t = threadIdx.x;
  int bid = blockIdx.x;                       // 1152
  int logical = (bid & 7) * 144 + (bid >> 3); // bijective XCD swizzle
  int och = logical / 576;                    // oc half
  int rem = logical % 576;
  int b = rem / 144;
  int tl = rem % 144;
  int h0 = (tl / 12) * 4;
  int w0 = (tl % 12) * 4;
  int s_ic = t >> 2;
  int s_row = t & 3;
  const float* xp = x + (size_t)b * 64 * 2304 + (size_t)s_ic * 2304;

  float4 X[3][3];
  bool hvr[3];
#pragma unroll
  for (int r = 0; r < 3; ++r) {
    int hh = h0 + s_row + r - 1;
    hvr[r] = (unsigned)hh < (unsigned)HX;
    int hc = min(max(hh, 0), HX - 1);
    const float* xr = xp + hc * WX;
#pragma unroll
    for (int q = 0; q < 3; ++q) {
      int cb = min(max(w0 - 4 + 4 * q, 0), WX - 4);   // clamped aligned base
      X[r][q] = *(const float4*)&xr[cb];
    }
  }
#pragma unroll
  for (int k = 0; k < 9; ++k) {
    int dy = k / 3 - 1, dx = k % 3 - 1;
    int r = dy + 1;
#pragma unroll
    for (int j = 0; j < 4; ++j) {
      int idx = j + dx + 4;                   // column (w0+j+dx) -> idx 3..8
      int q = idx >> 2, e = idx & 3;
      float val = (e == 0) ? X[r][q].x : (e == 1) ? X[r][q].y
                : (e == 2) ? X[r][q].z : X[r][q].w;
      bool cv = (unsigned)(w0 + j + dx) < (unsigned)WX;
      float v = (hvr[r] && cv) ? val : 0.f;
      sB[k][s_row * 4 + j][s_ic] = f2bf(v);
    }
  }
  __syncthreads();

  int w = t >> 6;
  int l = t & 63;
  int lr = l & 15;
  int lg = l >> 4;
  f32x4 acc[2] = {};
#pragma unroll
  for (int p = 0; p < 3; ++p) {
#pragma unroll
    for (int s = 0; s < 6; ++s) {
      int tapidx = p * 3 + (s >> 1);
      int c0 = (s & 1) * 32;
      bf16x8 bv = *(const bf16x8*)&sB[tapidx][lr][c0 + lg * 8];
#pragma unroll
      for (int m = 0; m < 2; ++m) {
        int mq = och * 8 + w * 2 + m;         // 0..15
        bf16x8 av = *(const bf16x8*)(ap2 +
            (size_t)((((p * 6 + s) * 16) + mq) * 64 + l) * 8);
        acc[m] = __builtin_amdgcn_mfma_f32_16x16x32_bf16(av, bv, acc[m], 0, 0, 0);
      }
    }
  }
  int prow = lr >> 2, pcol = lr & 3;
#pragma unroll
  for (int m = 0; m < 2; ++m) {
    int ocb = (och * 8 + w * 2 + m) * 16 + lg * 4;
    if (ocb < OMC) {
      float4 bb = *(const float4*)&bom[ocb];
      float bvv[4] = {bb.x, bb.y, bb.z, bb.w};
#pragma unroll
      for (int i = 0; i < 4; ++i) {
        om[((size_t)(b * OMC + ocb + i)) * 2304 + (h0 + prow) * WX + w0 + pcol] =
            acc[m][i] + bvv[i];
      }
    }
  }
}

// ---------- deform: triples in LDS, pinned pipelined bf16 gather + MFMA ----------
__global__ __launch_bounds__(256) void deform_mfma_kernel(
    const unsigned short* __restrict__ ytbf, const float* __restrict__ om,
    const unsigned short* __restrict__ ap1, const float* __restrict__ bdc,
    float* __restrict__ out) {
  __shared__ float sTy[72][16];                 // 4608 B  [k*8+g][px]
  __shared__ float sTx[72][16];                 // 4608 B
  __shared__ float sTm[72][16];                 // 4608 B
  __shared__ unsigned short sval[2][16][72];    // 4608 B   (total 18432 B)
  int t = threadIdx.x;
  int bid = blockIdx.x;                         // 2304
  int logical = (bid & 7) * 288 + (bid >> 3);   // bijective XCD swizzle
  int b = logical / 576;
  int tl = logical % 576;
  int h0 = (tl / 24) * 4;                       // 24 h-tiles of 4
  int w0 = (tl % 24) * 4;                       // 24 w-tiles of 4
  const float* omb = om + (size_t)b * OMC * 2304;
  const unsigned short* ytb = ytbf + (size_t)b * 9216 * 64;

  // ---- Phase A: compute all 1152 resize triples once ----
#pragma unroll
  for (int r = 0; r < 5; ++r) {
    int j = t + r * 256;
    if (j < 1152) {
      int k = j >> 7;                           // 0..8
      int g = (j >> 4) & 7;
      int px = j & 15;
      int gh = h0 + (px >> 2);
      int gw = w0 + (px & 3);
      float sh = fmaxf(gh * 0.5f - 0.25f, 0.f);
      float sw = fmaxf(gw * 0.5f - 0.25f, 0.f);
      int i0h = (int)sh; float th = sh - (float)i0h;
      int i0w = (int)sw; float tw = sw - (float)i0w;
      int i1h = min(i0h + 1, HX - 1);
      int i1w = min(i0w + 1, WX - 1);
      float r00 = (1.f - th) * (1.f - tw), r01 = (1.f - th) * tw;
      float r10 = th * (1.f - tw),         r11 = th * tw;
      int a00 = i0h * WX + i0w, a01 = i0h * WX + i1w;
      int a10 = i1h * WX + i0w, a11 = i1h * WX + i1w;
      const float* cy = omb + (size_t)(g * 18 + k * 2) * 2304;
      const float* cx = cy + 2304;
      const float* cm = omb + (size_t)(144 + g * 9 + k) * 2304;
      float oy = r00 * cy[a00] + r01 * cy[a01] + r10 * cy[a10] + r11 * cy[a11];
      float ox = r00 * cx[a00] + r01 * cx[a01] + r10 * cx[a10] + r11 * cx[a11];
      float mv = r00 * cm[a00] + r01 * cm[a01] + r10 * cm[a10] + r11 * cm[a11];
      int row = k * 8 + g;
      sTy[row][px] = (float)(gh + k / 3 - 1) + oy;
      sTx[row][px] = (float)(gw + k % 3 - 1) + ox;
      sTm[row][px] = 1.f / (1.f + __expf(-mv));
    }
  }

  int item = t >> 1;                            // 0..127 = g*16 + px
  int g = item >> 4;
  int px = item & 15;
  int cp = t & 1;                               // channel half of the 8-ch group
  int chb = g * 8 + cp * 4;

  int w = t >> 6;
  int l = t & 63;
  int lr = l & 15;
  int lg = l >> 4;

  __syncthreads();                              // triples ready

  ushort4 U[2][4];    // corner bf16x4 loads, slot tap&1 (2 VGPRs each)
  float W[2][4];      // corner weights, slot tap&1

  auto issueC = [&](int k, ushort4* Uo, float* Wo) {
    int row = k * 8 + g;
    float py = sTy[row][px], pxf = sTx[row][px], m = sTm[row][px];
    float y0f = floorf(py), x0f = floorf(pxf);
    float ty = py - y0f, tx = pxf - x0f;
    int y0 = (int)y0f, x0 = (int)x0f;
    int y1 = y0 + 1, x1 = x0 + 1;
    float w00 = (1.f - ty) * (1.f - tx) * m, w01 = (1.f - ty) * tx * m;
    float w10 = ty * (1.f - tx) * m,         w11 = ty * tx * m;
    Wo[0] = ((unsigned)y0 < HY && (unsigned)x0 < WY) ? w00 : 0.f;
    Wo[1] = ((unsigned)y0 < HY && (unsigned)x1 < WY) ? w01 : 0.f;
    Wo[2] = ((unsigned)y1 < HY && (unsigned)x0 < WY) ? w10 : 0.f;
    Wo[3] = ((unsigned)y1 < HY && (unsigned)x1 < WY) ? w11 : 0.f;
    int y0c = min(max(y0, 0), HY - 1), y1c = min(max(y1, 0), HY - 1);
    int x0c = min(max(x0, 0), WY - 1), x1c = min(max(x1, 0), WY - 1);
    Uo[0] = *(const ushort4*)(ytb + ((size_t)(y0c * WY + x0c) << 6) + chb);
    Uo[1] = *(const ushort4*)(ytb + ((size_t)(y0c * WY + x1c) << 6) + chb);
    Uo[2] = *(const ushort4*)(ytb + ((size_t)(y1c * WY + x0c) << 6) + chb);
    Uo[3] = *(const ushort4*)(ytb + ((size_t)(y1c * WY + x1c) << 6) + chb);
  };
  auto finishC = [&](const ushort4* Ui, const float* Wi, int buf) {
    float4 s0 = {0.f, 0.f, 0.f, 0.f};
#pragma unroll
    for (int c4 = 0; c4 < 4; ++c4) {
      float wgt = Wi[c4];
      s0.x += wgt * B2F(Ui[c4].x);
      s0.y += wgt * B2F(Ui[c4].y);
      s0.z += wgt * B2F(Ui[c4].z);
      s0.w += wgt * B2F(Ui[c4].w);
    }
    *(uint2*)&sval[buf][px][chb] = make_uint2(pk2(s0.x, s0.y), pk2(s0.z, s0.w));
  };

  // prologue: tap 0 corner loads in flight (pinned — may not sink)
  issueC(0, U[0], W[0]);
  __builtin_amdgcn_sched_barrier(0);

  f32x4 acc = {};
#pragma unroll
  for (int tp = 0; tp < 9; ++tp) {
    if (tp + 1 < 9) {                            // next tap: 1-iter flight
      issueC(tp + 1, U[(tp + 1) & 1], W[(tp + 1) & 1]);
      __builtin_amdgcn_sched_barrier(0);         // pin loads BEFORE finishC(tp)
    }
    finishC(U[tp & 1], W[tp & 1], tp & 1);       // waits only its own 4 loads
    __syncthreads();
    int p = tp / 3;
    int sl = (tp % 3) * 2;
#pragma unroll
    for (int half = 0; half < 2; ++half) {
      int s = sl + half;
      bf16x8 av = *(const bf16x8*)(ap1 +
          (size_t)(((p * 6 + s) * 4 + w) * 64 + l) * 8);
      bf16x8 bv = *(const bf16x8*)&sval[tp & 1][lr][half * 32 + lg * 8];
      acc = __builtin_amdgcn_mfma_f32_16x16x32_bf16(av, bv, acc, 0, 0, 0);
    }
    // finishC[tp+2] (same buf) is fenced by barrier[tp+1] which program-order
    // follows this MFMA's LDS reads on every wave.
  }

  // epilogue: bias + relu + store (oc = w*16+lg*4+i, px = lr in 4x4 tile)
  float4 bb = *(const float4*)&bdc[w * 16 + lg * 4];
  float bvv[4] = {bb.x, bb.y, bb.z, bb.w};
#pragma unroll
  for (int i = 0; i < 4; ++i) {
    int oc = w * 16 + lg * 4 + i;
    out[((size_t)(b * 64 + oc) * 96 + h0 + (lr >> 2)) * 96 + w0 + (lr & 3)] =
        fmaxf(acc[i] + bvv[i], 0.f);
  }
}

extern "C" void kernel_launch(void* const* d_in, const int* in_sizes, int n_in,
                              void* d_out, int out_size, void* d_ws, size_t ws_size,
                              hipStream_t stream) {
  const float* x = (const float*)d_in[0];
  const float* y = (const float*)d_in[1];
  const float* w_om = (const float*)d_in[2];
  const float* b_om = (const float*)d_in[3];
  const float* w_dc = (const float*)d_in[4];
  const float* b_dc = (const float*)d_in[5];
  float* out = (float*)d_out;

  float* om  = (float*)d_ws;                       // 1,990,656 f
  unsigned short* ap2 = (unsigned short*)(om + 1990656);   // 147,456 bf16
  unsigned short* ap1 = ap2 + 147456;              //  36,864 bf16
  unsigned short* ytbf = ap1 + 36864;              // 2,359,296 bf16

  prep_ytr_kernel<<<1296, 256, 0, stream>>>(w_om, w_dc, y, ap2, ap1, ytbf);
  conv_mfma_kernel<<<1152, 256, 0, stream>>>(x, ap2, b_om, om);
  deform_mfma_kernel<<<2304, 256, 0, stream>>>(ytbf, om, ap1, b_dc, out);
}

// Round 19
// 57.315 us; speedup vs baseline: 1.3619x; 1.0934x over previous
//
#include <hip/hip_runtime.h>
#include <math.h>

#define HX 48
#define WX 48
#define OMC 216
#define HY 96
#define WY 96

typedef __attribute__((ext_vector_type(8))) short bf16x8;
typedef __attribute__((ext_vector_type(4))) float f32x4;

__device__ inline unsigned short f2bf(float f) {
  unsigned u = __float_as_uint(f);
  return (unsigned short)((u + 0x7fffu + ((u >> 16) & 1u)) >> 16);  // RNE
}
__device__ inline unsigned pk2(float a, float b) {
  return (unsigned)f2bf(a) | ((unsigned)f2bf(b) << 16);
}
#define B2F(u) __uint_as_float((unsigned)(u) << 16)

// ws layout (floats):
//  om   @ 0          : 1,990,656
//  ap2  @ 1,990,656  :    73,728  (147,456 bf16)
//  ap1  @ 2,064,384  :    18,432  ( 36,864 bf16)
//  ytbf @ 2,082,816  : 1,179,648  (2,359,296 bf16: [b][g8][px9216][ch8])

// ---------- fused: prep (blocks 0..719) + ytr->bf16 group-major (720..1295) ----------
__global__ __launch_bounds__(256) void prep_ytr_kernel(
    const float* __restrict__ w_om, const float* __restrict__ w_dc,
    const float* __restrict__ y,
    unsigned short* __restrict__ ap2, unsigned short* __restrict__ ap1,
    unsigned short* __restrict__ ytbf) {
  __shared__ float tile[64][65];
  int bid = blockIdx.x;
  int t = threadIdx.x;
  if (bid < 720) {
    int idx = bid * 256 + t;                  // 0..184319
    if (idx < 147456) {
      int j = idx & 7;
      int tmp = idx >> 3;
      int l = tmp & 63; tmp >>= 6;
      int m = tmp & 15; tmp >>= 4;            // 0..17
      int s = tmp % 6, p = tmp / 6;
      int oc = m * 16 + (l & 15);
      int kk = s * 32 + (l >> 4) * 8 + j;     // 0..191
      int tap = kk >> 6, c = kk & 63;
      int k = p * 3 + tap;
      ap2[idx] = (oc < OMC) ? f2bf(w_om[oc * 576 + c * 9 + k]) : (unsigned short)0;
    } else {
      int i2 = idx - 147456;                  // < 36864
      int j = i2 & 7;
      int tmp = i2 >> 3;
      int l = tmp & 63; tmp >>= 6;
      int w = tmp & 3; tmp >>= 2;             // 0..17
      int s = tmp % 6, p = tmp / 6;
      int oc = w * 16 + (l & 15);
      int kk = s * 32 + (l >> 4) * 8 + j;
      int tap = kk >> 6, c = kk & 63;
      ap1[i2] = f2bf(w_dc[oc * 576 + c * 9 + p * 3 + tap]);
    }
  } else {
    int blk = bid - 720;                      // 576 = 4b * 144
    int b = blk / 144;
    int p0 = (blk % 144) * 64;
    int pl = t & 63;
    int cb = t >> 6;
#pragma unroll
    for (int i = 0; i < 16; ++i) {
      int c = cb * 16 + i;
      tile[c][pl] = y[((size_t)(b * 64 + c)) * 9216 + p0 + pl];
    }
    __syncthreads();
    int cw = t & 63;
    int pb = t >> 6;
#pragma unroll
    for (int i = 0; i < 16; ++i) {
      int p = pb * 16 + i;
      // group-major: [b][g][px][c8]
      ytbf[((size_t)((b * 8 + (cw >> 3)) * 9216) + p0 + p) * 8 + (cw & 7)] =
          f2bf(tile[cw][p]);
    }
  }
}

// ---------- conv (9 taps) via MFMA, oc-split; float4 register staging ----------
__global__ __launch_bounds__(256) void conv_mfma_kernel(
    const float* __restrict__ x, const unsigned short* __restrict__ ap2,
    const float* __restrict__ bom, float* __restrict__ om) {
  __shared__ unsigned short sB[9][16][72];    // 20736 B, [tap][px][c]
  int t = threadIdx.x;
  int bid = blockIdx.x;                       // 1152
  int logical = (bid & 7) * 144 + (bid >> 3); // bijective XCD swizzle
  int och = logical / 576;                    // oc half
  int rem = logical % 576;
  int b = rem / 144;
  int tl = rem % 144;
  int h0 = (tl / 12) * 4;
  int w0 = (tl % 12) * 4;
  int s_ic = t >> 2;
  int s_row = t & 3;
  const float* xp = x + (size_t)b * 64 * 2304 + (size_t)s_ic * 2304;

  float4 X[3][3];
  bool hvr[3];
#pragma unroll
  for (int r = 0; r < 3; ++r) {
    int hh = h0 + s_row + r - 1;
    hvr[r] = (unsigned)hh < (unsigned)HX;
    int hc = min(max(hh, 0), HX - 1);
    const float* xr = xp + hc * WX;
#pragma unroll
    for (int q = 0; q < 3; ++q) {
      int cb = min(max(w0 - 4 + 4 * q, 0), WX - 4);   // clamped aligned base
      X[r][q] = *(const float4*)&xr[cb];
    }
  }
#pragma unroll
  for (int k = 0; k < 9; ++k) {
    int dy = k / 3 - 1, dx = k % 3 - 1;
    int r = dy + 1;
#pragma unroll
    for (int j = 0; j < 4; ++j) {
      int idx = j + dx + 4;                   // column (w0+j+dx) -> idx 3..8
      int q = idx >> 2, e = idx & 3;
      float val = (e == 0) ? X[r][q].x : (e == 1) ? X[r][q].y
                : (e == 2) ? X[r][q].z : X[r][q].w;
      bool cv = (unsigned)(w0 + j + dx) < (unsigned)WX;
      float v = (hvr[r] && cv) ? val : 0.f;
      sB[k][s_row * 4 + j][s_ic] = f2bf(v);
    }
  }
  __syncthreads();

  int w = t >> 6;
  int l = t & 63;
  int lr = l & 15;
  int lg = l >> 4;
  f32x4 acc[2] = {};
#pragma unroll
  for (int p = 0; p < 3; ++p) {
#pragma unroll
    for (int s = 0; s < 6; ++s) {
      int tapidx = p * 3 + (s >> 1);
      int c0 = (s & 1) * 32;
      bf16x8 bv = *(const bf16x8*)&sB[tapidx][lr][c0 + lg * 8];
#pragma unroll
      for (int m = 0; m < 2; ++m) {
        int mq = och * 8 + w * 2 + m;         // 0..15
        bf16x8 av = *(const bf16x8*)(ap2 +
            (size_t)((((p * 6 + s) * 16) + mq) * 64 + l) * 8);
        acc[m] = __builtin_amdgcn_mfma_f32_16x16x32_bf16(av, bv, acc[m], 0, 0, 0);
      }
    }
  }
  int prow = lr >> 2, pcol = lr & 3;
#pragma unroll
  for (int m = 0; m < 2; ++m) {
    int ocb = (och * 8 + w * 2 + m) * 16 + lg * 4;
    if (ocb < OMC) {
      float4 bb = *(const float4*)&bom[ocb];
      float bvv[4] = {bb.x, bb.y, bb.z, bb.w};
#pragma unroll
      for (int i = 0; i < 4; ++i) {
        om[((size_t)(b * OMC + ocb + i)) * 2304 + (h0 + prow) * WX + w0 + pcol] =
            acc[m][i] + bvv[i];
      }
    }
  }
}

// ---------- deform: triples in LDS, pipelined group-major bf16 gather + MFMA ----------
__global__ __launch_bounds__(256) void deform_mfma_kernel(
    const unsigned short* __restrict__ ytbf, const float* __restrict__ om,
    const unsigned short* __restrict__ ap1, const float* __restrict__ bdc,
    float* __restrict__ out) {
  __shared__ float sTy[72][16];                 // 4608 B  [k*8+g][px]
  __shared__ float sTx[72][16];                 // 4608 B
  __shared__ float sTm[72][16];                 // 4608 B
  __shared__ unsigned short sval[2][16][72];    // 4608 B   (total 18432 B)
  int t = threadIdx.x;
  int bid = blockIdx.x;                         // 2304
  int logical = (bid & 7) * 288 + (bid >> 3);   // bijective XCD swizzle
  int b = logical / 576;
  int tl = logical % 576;
  int h0 = (tl / 24) * 4;                       // 24 h-tiles of 4
  int w0 = (tl % 24) * 4;                       // 24 w-tiles of 4
  const float* omb = om + (size_t)b * OMC * 2304;

  // ---- Phase A: compute all 1152 resize triples once ----
#pragma unroll
  for (int r = 0; r < 5; ++r) {
    int j = t + r * 256;
    if (j < 1152) {
      int k = j >> 7;                           // 0..8
      int g = (j >> 4) & 7;
      int px = j & 15;
      int gh = h0 + (px >> 2);
      int gw = w0 + (px & 3);
      float sh = fmaxf(gh * 0.5f - 0.25f, 0.f);
      float sw = fmaxf(gw * 0.5f - 0.25f, 0.f);
      int i0h = (int)sh; float th = sh - (float)i0h;
      int i0w = (int)sw; float tw = sw - (float)i0w;
      int i1h = min(i0h + 1, HX - 1);
      int i1w = min(i0w + 1, WX - 1);
      float r00 = (1.f - th) * (1.f - tw), r01 = (1.f - th) * tw;
      float r10 = th * (1.f - tw),         r11 = th * tw;
      int a00 = i0h * WX + i0w, a01 = i0h * WX + i1w;
      int a10 = i1h * WX + i0w, a11 = i1h * WX + i1w;
      const float* cy = omb + (size_t)(g * 18 + k * 2) * 2304;
      const float* cx = cy + 2304;
      const float* cm = omb + (size_t)(144 + g * 9 + k) * 2304;
      float oy = r00 * cy[a00] + r01 * cy[a01] + r10 * cy[a10] + r11 * cy[a11];
      float ox = r00 * cx[a00] + r01 * cx[a01] + r10 * cx[a10] + r11 * cx[a11];
      float mv = r00 * cm[a00] + r01 * cm[a01] + r10 * cm[a10] + r11 * cm[a11];
      int row = k * 8 + g;
      sTy[row][px] = (float)(gh + k / 3 - 1) + oy;
      sTx[row][px] = (float)(gw + k % 3 - 1) + ox;
      sTm[row][px] = 1.f / (1.f + __expf(-mv));
    }
  }

  int item = t >> 1;                            // 0..127 = g*16 + px
  int g = item >> 4;
  int px = item & 15;
  int cp = t & 1;                               // channel half of the 8-ch group
  int chb = g * 8 + cp * 4;
  // group-major base for this item's group, channel-half cp
  const unsigned short* ytg =
      ytbf + ((size_t)((logical / 576) * 8 + g) * 9216) * 8 + cp * 4;

  int w = t >> 6;
  int l = t & 63;
  int lr = l & 15;
  int lg = l >> 4;

  __syncthreads();                              // triples ready

  ushort4 U[2][4];    // corner bf16x4 loads, slot tap&1 (2 VGPRs each)
  float W[2][4];      // corner weights, slot tap&1

  auto issueC = [&](int k, ushort4* Uo, float* Wo) {
    int row = k * 8 + g;
    float py = sTy[row][px], pxf = sTx[row][px], m = sTm[row][px];
    float y0f = floorf(py), x0f = floorf(pxf);
    float ty = py - y0f, tx = pxf - x0f;
    int y0 = (int)y0f, x0 = (int)x0f;
    int y1 = y0 + 1, x1 = x0 + 1;
    float w00 = (1.f - ty) * (1.f - tx) * m, w01 = (1.f - ty) * tx * m;
    float w10 = ty * (1.f - tx) * m,         w11 = ty * tx * m;
    Wo[0] = ((unsigned)y0 < HY && (unsigned)x0 < WY) ? w00 : 0.f;
    Wo[1] = ((unsigned)y0 < HY && (unsigned)x1 < WY) ? w01 : 0.f;
    Wo[2] = ((unsigned)y1 < HY && (unsigned)x0 < WY) ? w10 : 0.f;
    Wo[3] = ((unsigned)y1 < HY && (unsigned)x1 < WY) ? w11 : 0.f;
    int y0c = min(max(y0, 0), HY - 1), y1c = min(max(y1, 0), HY - 1);
    int x0c = min(max(x0, 0), WY - 1), x1c = min(max(x1, 0), WY - 1);
    Uo[0] = *(const ushort4*)(ytg + ((size_t)(y0c * WY + x0c) << 3));
    Uo[1] = *(const ushort4*)(ytg + ((size_t)(y0c * WY + x1c) << 3));
    Uo[2] = *(const ushort4*)(ytg + ((size_t)(y1c * WY + x0c) << 3));
    Uo[3] = *(const ushort4*)(ytg + ((size_t)(y1c * WY + x1c) << 3));
  };
  auto finishC = [&](const ushort4* Ui, const float* Wi, int buf) {
    float4 s0 = {0.f, 0.f, 0.f, 0.f};
#pragma unroll
    for (int c4 = 0; c4 < 4; ++c4) {
      float wgt = Wi[c4];
      s0.x += wgt * B2F(Ui[c4].x);
      s0.y += wgt * B2F(Ui[c4].y);
      s0.z += wgt * B2F(Ui[c4].z);
      s0.w += wgt * B2F(Ui[c4].w);
    }
    *(uint2*)&sval[buf][px][chb] = make_uint2(pk2(s0.x, s0.y), pk2(s0.z, s0.w));
  };

  // prologue: tap 0 corner loads in flight (pinned — may not sink)
  issueC(0, U[0], W[0]);
  __builtin_amdgcn_sched_barrier(0);

  f32x4 acc = {};
#pragma unroll
  for (int tp = 0; tp < 9; ++tp) {
    if (tp + 1 < 9) {                            // next tap: 1-iter flight
      issueC(tp + 1, U[(tp + 1) & 1], W[(tp + 1) & 1]);
      __builtin_amdgcn_sched_barrier(0);         // pin loads BEFORE finishC(tp)
    }
    finishC(U[tp & 1], W[tp & 1], tp & 1);       // issued last iter
    __syncthreads();
    int p = tp / 3;
    int sl = (tp % 3) * 2;
#pragma unroll
    for (int half = 0; half < 2; ++half) {
      int s = sl + half;
      bf16x8 av = *(const bf16x8*)(ap1 +
          (size_t)(((p * 6 + s) * 4 + w) * 64 + l) * 8);
      bf16x8 bv = *(const bf16x8*)&sval[tp & 1][lr][half * 32 + lg * 8];
      acc = __builtin_amdgcn_mfma_f32_16x16x32_bf16(av, bv, acc, 0, 0, 0);
    }
    // finishC[tp+2] (same buf) is fenced by barrier[tp+1] which program-order
    // follows this MFMA's LDS reads on every wave.
  }

  // epilogue: bias + relu + store (oc = w*16+lg*4+i, px = lr in 4x4 tile)
  float4 bb = *(const float4*)&bdc[w * 16 + lg * 4];
  float bvv[4] = {bb.x, bb.y, bb.z, bb.w};
#pragma unroll
  for (int i = 0; i < 4; ++i) {
    int oc = w * 16 + lg * 4 + i;
    out[((size_t)(b * 64 + oc) * 96 + h0 + (lr >> 2)) * 96 + w0 + (lr & 3)] =
        fmaxf(acc[i] + bvv[i], 0.f);
  }
}

extern "C" void kernel_launch(void* const* d_in, const int* in_sizes, int n_in,
                              void* d_out, int out_size, void* d_ws, size_t ws_size,
                              hipStream_t stream) {
  const float* x = (const float*)d_in[0];
  const float* y = (const float*)d_in[1];
  const float* w_om = (const float*)d_in[2];
  const float* b_om = (const float*)d_in[3];
  const float* w_dc = (const float*)d_in[4];
  const float* b_dc = (const float*)d_in[5];
  float* out = (float*)d_out;

  float* om  = (float*)d_ws;                       // 1,990,656 f
  unsigned short* ap2 = (unsigned short*)(om + 1990656);   // 147,456 bf16
  unsigned short* ap1 = ap2 + 147456;              //  36,864 bf16
  unsigned short* ytbf = ap1 + 36864;              // 2,359,296 bf16

  prep_ytr_kernel<<<1296, 256, 0, stream>>>(w_om, w_dc, y, ap2, ap1, ytbf);
  conv_mfma_kernel<<<1152, 256, 0, stream>>>(x, ap2, b_om, om);
  deform_mfma_kernel<<<2304, 256, 0, stream>>>(ytbf, om, ap1, b_dc, out);
}